// Round 17
// baseline (174.064 us; speedup 1.0000x reference)
//
#include <hip/hip_runtime.h>
#include <math.h>

// Performer (FAVOR+) causal attention, MI355X gfx950.
// B=4 L=4096 E=512 H=8 M=128 DH=64. All MFMA = 16x16x32 bf16, dot-of-rows pattern.
// R17: 2-deep register prefetch in both GEMMs (loads issued 2 K-tiles ahead;
// ~2x latency runway for the vmcnt wait at WRITET). Numerically identical.

typedef unsigned short u16;
typedef short s8v __attribute__((ext_vector_type(8)));   // 8 bf16 (bits)
typedef unsigned short u4v __attribute__((ext_vector_type(4))); // 4 bf16 (bits)
typedef float f4v __attribute__((ext_vector_type(4)));

#define DN_    0.35355339059327379f   /* 64^-0.25 */
#define RATIO_ 0.08838834764831845f   /* 128^-0.5 */
#define EPS_   1e-5f

static __device__ __forceinline__ u16 f2bf(float x) {
  union { float f; unsigned u; } v; v.f = x;
  unsigned r = v.u + 0x7fffu + ((v.u >> 16) & 1u);
  return (u16)(r >> 16);
}
static __device__ __forceinline__ float bf2f(u16 b) {
  union { unsigned u; float f; } v; v.u = ((unsigned)b) << 16;
  return v.f;
}
static __device__ __forceinline__ unsigned fmax_key(float f) {
  union { float f; unsigned u; } v; v.f = f;
  return (v.u & 0x80000000u) ? ~v.u : (v.u | 0x80000000u);
}
static __device__ __forceinline__ float fmax_unkey(unsigned k) {
  union { unsigned u; float f; } v;
  v.u = (k & 0x80000000u) ? (k ^ 0x80000000u) : ~k;
  return v.f;
}
static __device__ __forceinline__ f4v mfma16(s8v a, s8v b, f4v c) {
  return __builtin_amdgcn_mfma_f32_16x16x32_bf16(a, b, c, 0, 0, 0);
}
// Barrier draining LDS ops only (register-destined global loads stay in flight).
static __device__ __forceinline__ void bar_lds() {
  asm volatile("s_waitcnt lgkmcnt(0)" ::: "memory");
  __builtin_amdgcn_s_barrier();
}
// 8x f32 -> 8x bf16 (RNE) via v_cvt_pk_bf16_f32 (no builtin on gfx950).
static __device__ __forceinline__ s8v pack8(f4v a, f4v b) {
  union { s8v v; unsigned u[4]; } r;
  asm("v_cvt_pk_bf16_f32 %0, %1, %2" : "=v"(r.u[0]) : "v"(a[0]), "v"(a[1]));
  asm("v_cvt_pk_bf16_f32 %0, %1, %2" : "=v"(r.u[1]) : "v"(a[2]), "v"(a[3]));
  asm("v_cvt_pk_bf16_f32 %0, %1, %2" : "=v"(r.u[2]) : "v"(b[0]), "v"(b[1]));
  asm("v_cvt_pk_bf16_f32 %0, %1, %2" : "=v"(r.u[3]) : "v"(b[2]), "v"(b[3]));
  return r.v;
}
// XOR-swizzled element offset in a [R][ldc] bf16 tile (16B-chunk ^ row&7).
static __device__ __forceinline__ int sw(int row, int col, int ldc) {
  int c3 = col >> 3;
  c3 = (c3 & ~7) | ((c3 ^ row) & 7);
  return row * ldc + (c3 << 3) + (col & 7);
}

// ---------------------------------------------------------------------------
// One-shot weight conversion: [Wq|Wk|Wv|W0] f32 -> bf16, proj*dn -> bf16.
__global__ __launch_bounds__(256) void convw_k(
    const float* __restrict__ Wq, const float* __restrict__ Wk,
    const float* __restrict__ Wv, const float* __restrict__ W0,
    const float* __restrict__ proj, u16* __restrict__ out) {
  const int i = blockIdx.x * 256 + threadIdx.x;  // 8-elem group, 132096 total
  const float* s;
  float scale = 1.f;
  if (i < 131072) {
    const int zz = i >> 15;
    s = (zz == 0 ? Wq : zz == 1 ? Wk : zz == 2 ? Wv : W0) + (size_t)(i & 32767) * 8;
  } else {
    s = proj + (size_t)(i - 131072) * 8;
    scale = DN_;
  }
  f4v a = *(const f4v*)s, b = *(const f4v*)(s + 4);
#pragma unroll
  for (int j = 0; j < 4; j++) { a[j] *= scale; b[j] *= scale; }
  *(s8v*)(out + (size_t)i * 8) = pack8(a, b);
}

// ---------------------------------------------------------------------------
// Fused q/k/v projection: z = blockIdx.z. z=0 -> q_b, z=1 -> k_b,
// z=2 -> transposed store directly into vT.
// A: [16384,512] f32, W: bf16. 128x128 tile, BK=64, 4 waves 2x2, grid (128,4,3).
// Double-buffered LDS + 2-deep register prefetch.
__global__ __launch_bounds__(256) void gemm3_k(
    const float* __restrict__ Aq, const float* __restrict__ Ak, const float* __restrict__ Av,
    const u16* __restrict__ Wb,
    const float* __restrict__ bq, const float* __restrict__ bk, const float* __restrict__ bv,
    u16* __restrict__ Cq, u16* __restrict__ Ck, u16* __restrict__ vT) {
  const int z = blockIdx.z;
  const float* Ap = (z == 0) ? Aq : (z == 1) ? Ak : Av;
  const u16* Bm = Wb + (size_t)z * 262144;
  const float* bias = (z == 0) ? bq : (z == 1) ? bk : bv;

  __shared__ u16 LB[4][8192];   // {Al0,Bl0,Al1,Bl1}; z=2 reuses first 32KB
  const int tid = threadIdx.x;
  const int r0 = blockIdx.x * 128, c0 = blockIdx.y * 128;
  const int lane = tid & 63, w = tid >> 6;
  const int l15 = lane & 15, l4 = lane >> 4;
  const int wr = (w >> 1) * 64, wc = (w & 1) * 64;
  const f4v z4 = {0.f, 0.f, 0.f, 0.f};
  f4v acc[4][4];
#pragma unroll
  for (int m = 0; m < 4; m++)
#pragma unroll
    for (int n = 0; n < 4; n++) acc[m][n] = z4;

#define DECLP(S)                                                              \
  f4v pa##S##00, pa##S##01, pa##S##10, pa##S##11,                             \
      pa##S##20, pa##S##21, pa##S##30, pa##S##31;                             \
  s8v pb##S##0, pb##S##1, pb##S##2, pb##S##3;
  DECLP(0) DECLP(1)

#define LOADT(S, kt)                                                          \
  {                                                                           \
    const int u0 = tid, u1 = tid + 256, u2 = tid + 512, u3 = tid + 768;       \
    const float* s0 = Ap + (size_t)(r0 + (u0 >> 3)) * 512 + (kt) + ((u0 & 7) << 3); \
    const float* s1 = Ap + (size_t)(r0 + (u1 >> 3)) * 512 + (kt) + ((u1 & 7) << 3); \
    const float* s2 = Ap + (size_t)(r0 + (u2 >> 3)) * 512 + (kt) + ((u2 & 7) << 3); \
    const float* s3 = Ap + (size_t)(r0 + (u3 >> 3)) * 512 + (kt) + ((u3 & 7) << 3); \
    pa##S##00 = *(const f4v*)s0; pa##S##01 = *(const f4v*)(s0 + 4);           \
    pa##S##10 = *(const f4v*)s1; pa##S##11 = *(const f4v*)(s1 + 4);           \
    pa##S##20 = *(const f4v*)s2; pa##S##21 = *(const f4v*)(s2 + 4);           \
    pa##S##30 = *(const f4v*)s3; pa##S##31 = *(const f4v*)(s3 + 4);           \
    pb##S##0 = *(const s8v*)(Bm + (size_t)(c0 + (u0 >> 3)) * 512 + (kt) + ((u0 & 7) << 3)); \
    pb##S##1 = *(const s8v*)(Bm + (size_t)(c0 + (u1 >> 3)) * 512 + (kt) + ((u1 & 7) << 3)); \
    pb##S##2 = *(const s8v*)(Bm + (size_t)(c0 + (u2 >> 3)) * 512 + (kt) + ((u2 & 7) << 3)); \
    pb##S##3 = *(const s8v*)(Bm + (size_t)(c0 + (u3 >> 3)) * 512 + (kt) + ((u3 & 7) << 3)); \
  }
#define WRITET(S, Ad, Bd)                                                     \
  {                                                                           \
    const int u0 = tid, u1 = tid + 256, u2 = tid + 512, u3 = tid + 768;       \
    const int d0 = sw(u0 >> 3, (u0 & 7) << 3, 64);                            \
    const int d1 = sw(u1 >> 3, (u1 & 7) << 3, 64);                            \
    const int d2 = sw(u2 >> 3, (u2 & 7) << 3, 64);                            \
    const int d3 = sw(u3 >> 3, (u3 & 7) << 3, 64);                            \
    *(s8v*)&(Ad)[d0] = pack8(pa##S##00, pa##S##01); *(s8v*)&(Bd)[d0] = pb##S##0; \
    *(s8v*)&(Ad)[d1] = pack8(pa##S##10, pa##S##11); *(s8v*)&(Bd)[d1] = pb##S##1; \
    *(s8v*)&(Ad)[d2] = pack8(pa##S##20, pa##S##21); *(s8v*)&(Bd)[d2] = pb##S##2; \
    *(s8v*)&(Ad)[d3] = pack8(pa##S##30, pa##S##31); *(s8v*)&(Bd)[d3] = pb##S##3; \
  }

  LOADT(0, 0);
  WRITET(0, LB[0], LB[1]);
  LOADT(1, 64);                   // tile1 in flight across the barrier
  bar_lds();

#pragma unroll
  for (int t = 0; t < 8; t++) {
    u16* const Ac = LB[(t & 1) * 2];
    u16* const Bc = LB[(t & 1) * 2 + 1];
    u16* const An = LB[((t + 1) & 1) * 2];
    u16* const Bn = LB[((t + 1) & 1) * 2 + 1];
    if (t < 6) {                  // issue tile t+2 into the set freed at t
      if ((t & 1) == 0) {
        LOADT(0, (t + 2) * 64);
      } else {
        LOADT(1, (t + 2) * 64);
      }
    }
#pragma unroll
    for (int ks = 0; ks < 2; ks++) {
      s8v af[4], bf[4];
#pragma unroll
      for (int m = 0; m < 4; m++)
        af[m] = *(const s8v*)&Ac[sw(wr + m * 16 + l15, ks * 32 + l4 * 8, 64)];
#pragma unroll
      for (int n = 0; n < 4; n++)
        bf[n] = *(const s8v*)&Bc[sw(wc + n * 16 + l15, ks * 32 + l4 * 8, 64)];
#pragma unroll
      for (int m = 0; m < 4; m++)
#pragma unroll
        for (int n = 0; n < 4; n++) acc[m][n] = mfma16(af[m], bf[n], acc[m][n]);
    }
    if (t < 7) {                  // write tile t+1 (issued at t-1: ~2-phase runway)
      if ((t & 1) == 0) {
        WRITET(1, An, Bn);
      } else {
        WRITET(0, An, Bn);
      }
    }
    bar_lds();
  }
#undef LOADT
#undef WRITET
#undef DECLP

  if (z == 2) {
    // scatter biased bf16 tile into LB as [channel][l-chunk-swizzled]
    u16* const T = &LB[0][0];  // 16384 u16 (LB[0]+LB[1] contiguous)
#pragma unroll
    for (int n = 0; n < 4; n++) {
      const int cc = wc + n * 16 + l15;
      const float bv_ = bias[c0 + cc];
#pragma unroll
      for (int m = 0; m < 4; m++)
#pragma unroll
        for (int r = 0; r < 4; r++) {
          const int ll = wr + m * 16 + l4 * 4 + r;
          const int ch = ll >> 3;
          const int chs = (ch & 8) | ((ch ^ cc) & 7);
          T[cc * 128 + chs * 8 + (ll & 7)] = f2bf(acc[m][n][r] + bv_);
        }
    }
    __syncthreads();
    const int b = r0 >> 12, l0 = r0 & 4095;
    for (int u = tid; u < 2048; u += 256) {
      const int cc = u >> 4, ch = u & 15;
      const int chs = (ch & 8) | ((ch ^ cc) & 7);
      const s8v o = *(const s8v*)&T[cc * 128 + chs * 8];
      *(s8v*)(vT + ((size_t)(b * 512 + c0 + cc)) * 4096 + l0 + ch * 8) = o;
    }
    return;
  }
  u16* const Cp = (z == 0) ? Cq : Ck;
#pragma unroll
  for (int n = 0; n < 4; n++) {
    const int col = c0 + wc + n * 16 + l15;
    const float bv_ = bias[col];
#pragma unroll
    for (int m = 0; m < 4; m++)
#pragma unroll
      for (int r = 0; r < 4; r++) {
        const int row = r0 + wr + m * 16 + l4 * 4 + r;
        Cp[(size_t)row * 512 + col] = f2bf(acc[m][n][r] + bv_);
      }
  }
}

// ---------------------------------------------------------------------------
// Final GEMM: C = A @ W0^T + b0. A bf16, W0b bf16, C f32. 128x128 tile,
// grid (128,4). Double-buffered LDS + 2-deep register prefetch.
__global__ __launch_bounds__(256) void gemm_bt(const u16* __restrict__ Ap,
                                               const u16* __restrict__ Bm,
                                               const float* __restrict__ bias,
                                               float* __restrict__ Cp) {
  __shared__ u16 LB[4][8192];   // {Al0,Bl0,Al1,Bl1}
  const int tid = threadIdx.x;
  const int r0 = blockIdx.x * 128, c0 = blockIdx.y * 128;
  const int lane = tid & 63, w = tid >> 6;
  const int l15 = lane & 15, l4 = lane >> 4;
  const int wr = (w >> 1) * 64, wc = (w & 1) * 64;
  const f4v z = {0.f, 0.f, 0.f, 0.f};
  f4v acc[4][4];
#pragma unroll
  for (int m = 0; m < 4; m++)
#pragma unroll
    for (int n = 0; n < 4; n++) acc[m][n] = z;

#define DECLP(S) s8v qa##S##0, qa##S##1, qa##S##2, qa##S##3,                  \
                     qb##S##0, qb##S##1, qb##S##2, qb##S##3;
  DECLP(0) DECLP(1)
#define LOADT(S, kt)                                                          \
  {                                                                           \
    const int u0 = tid, u1 = tid + 256, u2 = tid + 512, u3 = tid + 768;       \
    qa##S##0 = *(const s8v*)(Ap + (size_t)(r0 + (u0 >> 3)) * 512 + (kt) + ((u0 & 7) << 3)); \
    qa##S##1 = *(const s8v*)(Ap + (size_t)(r0 + (u1 >> 3)) * 512 + (kt) + ((u1 & 7) << 3)); \
    qa##S##2 = *(const s8v*)(Ap + (size_t)(r0 + (u2 >> 3)) * 512 + (kt) + ((u2 & 7) << 3)); \
    qa##S##3 = *(const s8v*)(Ap + (size_t)(r0 + (u3 >> 3)) * 512 + (kt) + ((u3 & 7) << 3)); \
    qb##S##0 = *(const s8v*)(Bm + (size_t)(c0 + (u0 >> 3)) * 512 + (kt) + ((u0 & 7) << 3)); \
    qb##S##1 = *(const s8v*)(Bm + (size_t)(c0 + (u1 >> 3)) * 512 + (kt) + ((u1 & 7) << 3)); \
    qb##S##2 = *(const s8v*)(Bm + (size_t)(c0 + (u2 >> 3)) * 512 + (kt) + ((u2 & 7) << 3)); \
    qb##S##3 = *(const s8v*)(Bm + (size_t)(c0 + (u3 >> 3)) * 512 + (kt) + ((u3 & 7) << 3)); \
  }
#define WRITET(S, Ad, Bd)                                                     \
  {                                                                           \
    const int u0 = tid, u1 = tid + 256, u2 = tid + 512, u3 = tid + 768;       \
    const int d0 = sw(u0 >> 3, (u0 & 7) << 3, 64);                            \
    const int d1 = sw(u1 >> 3, (u1 & 7) << 3, 64);                            \
    const int d2 = sw(u2 >> 3, (u2 & 7) << 3, 64);                            \
    const int d3 = sw(u3 >> 3, (u3 & 7) << 3, 64);                            \
    *(s8v*)&(Ad)[d0] = qa##S##0; *(s8v*)&(Bd)[d0] = qb##S##0;                 \
    *(s8v*)&(Ad)[d1] = qa##S##1; *(s8v*)&(Bd)[d1] = qb##S##1;                 \
    *(s8v*)&(Ad)[d2] = qa##S##2; *(s8v*)&(Bd)[d2] = qb##S##2;                 \
    *(s8v*)&(Ad)[d3] = qa##S##3; *(s8v*)&(Bd)[d3] = qb##S##3;                 \
  }

  LOADT(0, 0);
  WRITET(0, LB[0], LB[1]);
  LOADT(1, 64);
  bar_lds();

#pragma unroll
  for (int t = 0; t < 8; t++) {
    u16* const Ac = LB[(t & 1) * 2];
    u16* const Bc = LB[(t & 1) * 2 + 1];
    u16* const An = LB[((t + 1) & 1) * 2];
    u16* const Bn = LB[((t + 1) & 1) * 2 + 1];
    if (t < 6) {
      if ((t & 1) == 0) {
        LOADT(0, (t + 2) * 64);
      } else {
        LOADT(1, (t + 2) * 64);
      }
    }
#pragma unroll
    for (int ks = 0; ks < 2; ks++) {
      s8v af[4], bf[4];
#pragma unroll
      for (int m = 0; m < 4; m++)
        af[m] = *(const s8v*)&Ac[sw(wr + m * 16 + l15, ks * 32 + l4 * 8, 64)];
#pragma unroll
      for (int n = 0; n < 4; n++)
        bf[n] = *(const s8v*)&Bc[sw(wc + n * 16 + l15, ks * 32 + l4 * 8, 64)];
#pragma unroll
      for (int m = 0; m < 4; m++)
#pragma unroll
        for (int n = 0; n < 4; n++) acc[m][n] = mfma16(af[m], bf[n], acc[m][n]);
    }
    if (t < 7) {
      if ((t & 1) == 0) {
        WRITET(1, An, Bn);
      } else {
        WRITET(0, An, Bn);
      }
    }
    bar_lds();
  }
#undef LOADT
#undef WRITET
#undef DECLP

#pragma unroll
  for (int n = 0; n < 4; n++) {
    const int col = c0 + wc + n * 16 + l15;
    const float bv = bias[col];
#pragma unroll
    for (int m = 0; m < 4; m++)
#pragma unroll
      for (int r = 0; r < 4; r++) {
        const int row = r0 + wr + m * 16 + l4 * 4 + r;
        Cp[(size_t)row * 512 + col] = acc[m][n][r] + bv;
      }
  }
}

// ---------------------------------------------------------------------------
// Merged feature-map pass: blocks 0..1023 = query (MODE0 -> qp),
// blocks 1024..2047 = key pass1 (MODE1 -> global per-(b,h) max atomics).
__global__ __launch_bounds__(256) void feat01_k(const u16* __restrict__ q_b,
                                                const u16* __restrict__ k_b,
                                                const u16* __restrict__ pDN,
                                                u16* __restrict__ qp,
                                                unsigned* __restrict__ slots) {
  __shared__ u16 Xl[128 * 64];
  __shared__ u16 Pl[128 * 64];
  __shared__ float diag_l[128];
  __shared__ unsigned hmax8[8];
  const int mode = blockIdx.x >> 10;
  const int r0 = (blockIdx.x & 1023) * 128;
  const u16* X = mode ? k_b : q_b;
  const int tid = threadIdx.x;
  if (mode && tid < 8) hmax8[tid] = 0u;
  for (int u = tid; u < 1024; u += 256) {
    const int row = u >> 3, c8 = (u & 7) << 3;
    *(s8v*)&Xl[sw(row, c8, 64)] = *(const s8v*)(X + (size_t)r0 * 64 + u * 8);
    *(s8v*)&Pl[sw(row, c8, 64)] = *(const s8v*)(pDN + u * 8);
  }
  __syncthreads();
  if (!mode && tid < 128) {
    float s = 0.f;
#pragma unroll
    for (int c = 0; c < 8; c++) {
      s8v v = *(const s8v*)&Xl[sw(tid, c * 8, 64)];
#pragma unroll
      for (int jj = 0; jj < 8; jj++) { float x = bf2f((u16)v[jj]); s += x * x; }
    }
    diag_l[tid] = 0.0625f * s;  // 0.5*dn^2
  }
  __syncthreads();
  const int lane = tid & 63, w = tid >> 6, l15 = lane & 15, l4 = lane >> 4;
  const f4v z = {0.f, 0.f, 0.f, 0.f};
  f4v acc[2][8];
#pragma unroll
  for (int m = 0; m < 2; m++)
#pragma unroll
    for (int n = 0; n < 8; n++) acc[m][n] = z;
#pragma unroll
  for (int ks = 0; ks < 2; ks++) {
    s8v af[2];
#pragma unroll
    for (int m = 0; m < 2; m++)
      af[m] = *(const s8v*)&Xl[sw(w * 32 + m * 16 + l15, ks * 32 + l4 * 8, 64)];
#pragma unroll
    for (int n = 0; n < 8; n++) {
      const s8v bf = *(const s8v*)&Pl[sw(n * 16 + l15, ks * 32 + l4 * 8, 64)];
#pragma unroll
      for (int m = 0; m < 2; m++) acc[m][n] = mfma16(af[m], bf, acc[m][n]);
    }
  }
#pragma unroll
  for (int m = 0; m < 2; m++)
#pragma unroll
    for (int r = 0; r < 4; r++) {
      const int rowl = w * 32 + m * 16 + l4 * 4 + r;
      const int R = r0 + rowl;
      float mx = acc[m][0][r];
#pragma unroll
      for (int n = 1; n < 8; n++) mx = fmaxf(mx, acc[m][n][r]);
      mx = fmaxf(mx, __shfl_xor(mx, 1, 64));
      mx = fmaxf(mx, __shfl_xor(mx, 2, 64));
      mx = fmaxf(mx, __shfl_xor(mx, 4, 64));
      mx = fmaxf(mx, __shfl_xor(mx, 8, 64));
      if (mode) {
        if (l15 == 0) atomicMax(&hmax8[(l4 * 4 + r) & 7], fmax_key(mx));
      } else {
        const float sub = diag_l[rowl] + mx;
        const size_t ob = (size_t)R * 128 + l15;
#pragma unroll
        for (int n = 0; n < 8; n++)
          qp[ob + n * 16] = f2bf(RATIO_ * (expf(acc[m][n][r] - sub) + EPS_));
      }
    }
  if (mode) {
    __syncthreads();
    if (tid < 8) atomicMax(&slots[((r0 >> 15) << 3) | tid], hmax8[tid]);
  }
}

// ---------------------------------------------------------------------------
// Fused key pass 2 + scan1. One (bh, chunk) per block over 128 l-rows:
// recompute dash, exp with global max -> write kp; build kp^T tile in LDS (S);
// then ST[d][m] = sum_l v[l,d]*kp[l,m] via MFMA from S + Vl, plus colsum.
__global__ __launch_bounds__(256) void featsc_k(const u16* __restrict__ k_b,
                                                const u16* __restrict__ pDN,
                                                const u16* __restrict__ vT,
                                                const unsigned* __restrict__ slots,
                                                u16* __restrict__ kp,
                                                u16* __restrict__ st,
                                                float* __restrict__ colsum) {
  __shared__ u16 S[16384];   // Xl=[0:8192), Pl=[8192:16384); then kp^T tile [m][l]
  __shared__ u16 Vl[8192];   // vT tile [d=64][l=128] sw-layout
  __shared__ float diag_l[128];
  u16* const Xl = S;
  u16* const Pl = S + 8192;
  const int c = blockIdx.x, bh = blockIdx.y;
  const int b = bh >> 3, h = bh & 7;
  const int l0 = c * 128;
  const int tid = threadIdx.x;
  for (int u = tid; u < 1024; u += 256) {
    const int row = u >> 3, c8 = (u & 7) << 3;
    *(s8v*)&Xl[sw(row, c8, 64)] =
        *(const s8v*)(k_b + ((size_t)(b * 4096 + l0 + row)) * 512 + h * 64 + c8);
    *(s8v*)&Pl[sw(row, c8, 64)] = *(const s8v*)(pDN + u * 8);
  }
  for (int u = tid; u < 1024; u += 256) {
    const int row = u >> 4, c8 = (u & 15) * 8;
    *(s8v*)&Vl[sw(row, c8, 128)] =
        *(const s8v*)(vT + ((size_t)(bh * 64 + row)) * 4096 + c * 128 + c8);
  }
  __syncthreads();
  if (tid < 128) {
    float s = 0.f;
#pragma unroll
    for (int cc = 0; cc < 8; cc++) {
      s8v v = *(const s8v*)&Xl[sw(tid, cc * 8, 64)];
#pragma unroll
      for (int jj = 0; jj < 8; jj++) { float x = bf2f((u16)v[jj]); s += x * x; }
    }
    diag_l[tid] = 0.0625f * s;
  }
  __syncthreads();
  const int lane = tid & 63, w = tid >> 6, l15 = lane & 15, l4 = lane >> 4;
  const f4v z = {0.f, 0.f, 0.f, 0.f};
  f4v acc[2][8];
#pragma unroll
  for (int m = 0; m < 2; m++)
#pragma unroll
    for (int n = 0; n < 8; n++) acc[m][n] = z;
#pragma unroll
  for (int ks = 0; ks < 2; ks++) {
    s8v af[2];
#pragma unroll
    for (int m = 0; m < 2; m++)
      af[m] = *(const s8v*)&Xl[sw(w * 32 + m * 16 + l15, ks * 32 + l4 * 8, 64)];
#pragma unroll
    for (int n = 0; n < 8; n++) {
      const s8v bf = *(const s8v*)&Pl[sw(n * 16 + l15, ks * 32 + l4 * 8, 64)];
#pragma unroll
      for (int m = 0; m < 2; m++) acc[m][n] = mfma16(af[m], bf, acc[m][n]);
    }
  }
  const float gmax = fmax_unkey(slots[bh]);
  __syncthreads();   // all Xl/Pl reads done; S becomes the kp^T tile
#pragma unroll
  for (int mm = 0; mm < 2; mm++)
#pragma unroll
    for (int r = 0; r < 4; r++) {
      const int ll = w * 32 + mm * 16 + l4 * 4 + r;
      const float sub = diag_l[ll] + gmax;
      const size_t ob = ((size_t)(b * 4096 + l0 + ll) * 8 + h) * 128 + l15;
#pragma unroll
      for (int n = 0; n < 8; n++) {
        const u16 val = f2bf(RATIO_ * (expf(acc[mm][n][r] - sub) + EPS_));
        kp[ob + n * 16] = val;
        const int m = n * 16 + l15;
        S[sw(m, ll, 128)] = val;
      }
    }
  __syncthreads();

  // scan1 part: ST[d=64][m=128] = sum_l Vl[d][l] * S[m][l]; colsum[m] = sum_l S[m][l]
  f4v acc1[8];
#pragma unroll
  for (int n = 0; n < 8; n++) acc1[n] = z;
#pragma unroll
  for (int ks = 0; ks < 4; ks++) {
    const s8v af = *(const s8v*)&Vl[sw(w * 16 + l15, ks * 32 + l4 * 8, 128)];
#pragma unroll
    for (int n = 0; n < 8; n++) {
      const s8v bf = *(const s8v*)&S[sw(n * 16 + l15, ks * 32 + l4 * 8, 128)];
      acc1[n] = mfma16(af, bf, acc1[n]);
    }
  }
  if (tid < 128) {
    float s = 0.f;
#pragma unroll
    for (int j8 = 0; j8 < 16; j8++) {
      s8v v = *(const s8v*)&S[sw(tid, j8 * 8, 128)];
#pragma unroll
      for (int jj = 0; jj < 8; jj++) s += bf2f((u16)v[jj]);
    }
    colsum[((size_t)(bh * 32 + c)) * 128 + tid] = s;
  }
  const size_t base = ((size_t)(bh * 32 + c)) * 8192;
#pragma unroll
  for (int n = 0; n < 8; n++)
#pragma unroll
    for (int r = 0; r < 4; r++)
      st[base + (w * 16 + l4 * 4 + r) * 128 + n * 16 + l15] = f2bf(acc1[n][r]);
}

// merged scan phase 2 + kpref: grid (9, 32). seg<8: in-place exclusive prefix
// of st; seg==8: exclusive prefix of colsum -> kpref (threads 0..127).
__global__ __launch_bounds__(256) void scan2p_k(u16* __restrict__ st,
                                                const float* __restrict__ colsum,
                                                float* __restrict__ kpref) {
  const int seg = blockIdx.x, bh = blockIdx.y, tid = threadIdx.x;
  if (seg < 8) {
    const int e0 = seg * 1024 + tid * 4;
    float acc[4] = {0.f, 0.f, 0.f, 0.f};
    for (int c = 0; c < 32; c++) {
      u16* p = st + ((size_t)(bh * 32 + c)) * 8192 + e0;
      u4v v = *(u4v*)p, o;
#pragma unroll
      for (int j = 0; j < 4; j++) {
        const float x = bf2f(v[j]);
        o[j] = f2bf(acc[j]);
        acc[j] += x;
      }
      *(u4v*)p = o;
    }
  } else if (tid < 128) {
    float ka = 0.f;
    for (int c = 0; c < 32; c++) {
      kpref[(bh * 32 + c) * 128 + tid] = ka;
      ka += colsum[(bh * 32 + c) * 128 + tid];
    }
  }
}

// scan phase 3 (merged halves): one 512-thread block per (chunk, bh).
__global__ __launch_bounds__(512) void scan3_k(const u16* __restrict__ qp,
                                               const u16* __restrict__ kp,
                                               const u16* __restrict__ vT,
                                               const u16* __restrict__ st,
                                               const float* __restrict__ kpref,
                                               u16* __restrict__ attn) {
  __shared__ u16 Ql[128 * 128];  // 32KB; front 16KB reused as Vl in AV phase
  __shared__ u16 Kr[128 * 128];  // 32KB; reused as Al(128x128) in AV phase
  const int c = blockIdx.x, bh = blockIdx.y;
  const int b = bh >> 3, h = bh & 7;
  const int tid = threadIdx.x, lane = tid & 63, w = tid >> 6;
  const int l15 = lane & 15, l4 = lane >> 4;
  const size_t Rbase = ((size_t)(b * 4096 + c * 128)) * 8 + h;

  for (int u = tid; u < 2048; u += 512) {
    const int row = u >> 4, c8 = (u & 15) * 8;
    *(s8v*)&Ql[sw(row, c8, 128)] =
        *(const s8v*)(qp + (Rbase + (size_t)row * 8) * 128 + c8);
    *(s8v*)&Kr[sw(row, c8, 128)] =
        *(const s8v*)(kp + (Rbase + (size_t)row * 8) * 128 + c8);
  }
  __syncthreads();

  const f4v z = {0.f, 0.f, 0.f, 0.f};
  f4v sc[8];
#pragma unroll
  for (int n = 0; n < 8; n++) sc[n] = z;
#pragma unroll
  for (int ks = 0; ks < 4; ks++) {
    const s8v af = *(const s8v*)&Ql[sw(w * 16 + l15, ks * 32 + l4 * 8, 128)];
#pragma unroll
    for (int n = 0; n < 8; n++) {
      const s8v bf = *(const s8v*)&Kr[sw(n * 16 + l15, ks * 32 + l4 * 8, 128)];
      sc[n] = mfma16(af, bf, sc[n]);
    }
  }
  const int lb = w * 16 + l4 * 4;
  float rs[4];
#pragma unroll
  for (int r = 0; r < 4; r++) {
    float s = 0.f;
#pragma unroll
    for (int n = 0; n < 8; n++) {
      const int col = n * 16 + l15;
      const float v = (col <= lb + r) ? sc[n][r] : 0.f;
      sc[n][r] = v;
      s += v;
    }
    s += __shfl_xor(s, 1, 64);
    s += __shfl_xor(s, 2, 64);
    s += __shfl_xor(s, 4, 64);
    s += __shfl_xor(s, 8, 64);
    rs[r] = s;
  }
  __syncthreads();

  {
    const u16* pref = st + ((size_t)(bh * 32 + c)) * 8192;
    for (int u = tid; u < 1024; u += 512) {
      const int row = u >> 4, c8 = (u & 15) * 8;
      *(s8v*)&Kr[sw(row, c8, 128)] = *(const s8v*)(pref + u * 8);
    }
    if (tid < 128) Kr[sw(64, tid, 128)] = f2bf(kpref[(bh * 32 + c) * 128 + tid]);
    for (int i = tid; i < 15 * 128; i += 512) Kr[65 * 128 + i] = 0;
  }
  __syncthreads();

  f4v acc2[5];
#pragma unroll
  for (int n = 0; n < 5; n++) acc2[n] = z;
#pragma unroll
  for (int ks = 0; ks < 4; ks++) {
    const s8v af = *(const s8v*)&Ql[sw(w * 16 + l15, ks * 32 + l4 * 8, 128)];
#pragma unroll
    for (int n = 0; n < 5; n++) {
      const s8v bf = *(const s8v*)&Kr[sw(n * 16 + l15, ks * 32 + l4 * 8, 128)];
      acc2[n] = mfma16(af, bf, acc2[n]);
    }
  }
  float din[4];
#pragma unroll
  for (int r = 0; r < 4; r++) {
    float s = acc2[4][r];
    s += __shfl_xor(s, 1, 64);
    s += __shfl_xor(s, 2, 64);
    s += __shfl_xor(s, 4, 64);
    s += __shfl_xor(s, 8, 64);
    din[r] = s;
  }
  __syncthreads();

#pragma unroll
  for (int n = 0; n < 8; n++)
#pragma unroll
    for (int r = 0; r < 4; r++)
      Kr[sw(w * 16 + l4 * 4 + r, n * 16 + l15, 128)] = f2bf(sc[n][r]);
  for (int u = tid; u < 1024; u += 512) {
    const int row = u >> 4, c8 = (u & 15) * 8;
    *(s8v*)&Ql[sw(row, c8, 128)] =
        *(const s8v*)(vT + ((size_t)(bh * 64 + row)) * 4096 + c * 128 + c8);
  }
  __syncthreads();

#pragma unroll
  for (int ks = 0; ks < 4; ks++) {
    const s8v af = *(const s8v*)&Kr[sw(w * 16 + l15, ks * 32 + l4 * 8, 128)];
#pragma unroll
    for (int n = 0; n < 4; n++) {
      const s8v bf = *(const s8v*)&Ql[sw(n * 16 + l15, ks * 32 + l4 * 8, 128)];
      acc2[n] = mfma16(af, bf, acc2[n]);
    }
  }
#pragma unroll
  for (int r = 0; r < 4; r++) {
    const float den = rs[r] + din[r];
    const int lrow = w * 16 + l4 * 4 + r;
    const size_t ob = ((size_t)(b * 4096 + c * 128 + lrow)) * 512 + h * 64;
#pragma unroll
    for (int n = 0; n < 4; n++)
      attn[ob + n * 16 + l15] = f2bf(acc2[n][r] / den);
  }
}

// ---------------------------------------------------------------------------
extern "C" void kernel_launch(void* const* d_in, const int* in_sizes, int n_in,
                              void* d_out, int out_size, void* d_ws, size_t ws_size,
                              hipStream_t stream) {
  const float* query = (const float*)d_in[0];
  const float* key   = (const float*)d_in[1];
  const float* value = (const float*)d_in[2];
  const float* Wq = (const float*)d_in[3];
  const float* Wk = (const float*)d_in[4];
  const float* Wv = (const float*)d_in[5];
  const float* W0 = (const float*)d_in[6];
  const float* bq = (const float*)d_in[7];
  const float* bk = (const float*)d_in[8];
  const float* bv = (const float*)d_in[9];
  const float* b0 = (const float*)d_in[10];
  const float* proj = (const float*)d_in[11];

  char* ws = (char*)d_ws;
  const size_t MB = 1u << 20;
  u16* kp   = (u16*)(ws + 0);            // 32MB
  u16* k_b  = (u16*)(ws + 32 * MB);      // 16MB
  u16* attn = (u16*)(ws + 32 * MB);      // alias k_b (dead after featsc)
  float* colsum = (float*)(ws + 32 * MB);// 512KB alias (dead before attn write)
  u16* qp   = (u16*)(ws + 48 * MB);      // 32MB
  u16* q_b  = (u16*)(ws + 80 * MB);      // 16MB
  u16* st   = (u16*)(ws + 112 * MB);     // 16MB
  u16* vT   = (u16*)(ws + 128 * MB);     // 16MB
  float* kpref    = (float*)(ws + 144 * MB);             // 512KB
  unsigned* slots = (unsigned*)(ws + 144 * MB + 524288); // 128B
  u16* Wb   = (u16*)(ws + 145 * MB);     // [Wq|Wk|Wv|W0] bf16 + dn*proj bf16
  u16* pDN  = Wb + 4 * 262144;

  (void)hipMemsetAsync(slots, 0, 32 * sizeof(unsigned), stream);

  dim3 blk(256);
  convw_k<<<dim3(516), blk, 0, stream>>>(Wq, Wk, Wv, W0, proj, Wb);
  gemm3_k<<<dim3(128, 4, 3), blk, 0, stream>>>(query, key, value, Wb,
                                               bq, bk, bv, q_b, k_b, vT);
  feat01_k<<<dim3(2048), blk, 0, stream>>>(q_b, k_b, pDN, qp, slots);
  featsc_k<<<dim3(32, 32), blk, 0, stream>>>(k_b, pDN, vT, slots, kp, st, colsum);
  scan2p_k<<<dim3(9, 32), blk, 0, stream>>>(st, colsum, kpref);
  scan3_k<<<dim3(32, 32), dim3(512), 0, stream>>>(qp, kp, vT, st, kpref, attn);
  gemm_bt<<<dim3(128, 4), blk, 0, stream>>>(attn, Wb + 3 * 262144, b0, (float*)d_out);
}

// Round 18
// 171.618 us; speedup vs baseline: 1.0143x; 1.0143x over previous
//
#include <hip/hip_runtime.h>
#include <math.h>

// Performer (FAVOR+) causal attention, MI355X gfx950.
// B=4 L=4096 E=512 H=8 M=128 DH=64. All MFMA = 16x16x32 bf16, dot-of-rows pattern.
// R18 (final): revert to R16 best (172.27us). scan3 merged halves; double-buffered
// GEMMs; fused v-transpose/feat/scan1; kpT eliminated; merged small launches.

typedef unsigned short u16;
typedef short s8v __attribute__((ext_vector_type(8)));   // 8 bf16 (bits)
typedef unsigned short u4v __attribute__((ext_vector_type(4))); // 4 bf16 (bits)
typedef float f4v __attribute__((ext_vector_type(4)));

#define DN_    0.35355339059327379f   /* 64^-0.25 */
#define RATIO_ 0.08838834764831845f   /* 128^-0.5 */
#define EPS_   1e-5f

static __device__ __forceinline__ u16 f2bf(float x) {
  union { float f; unsigned u; } v; v.f = x;
  unsigned r = v.u + 0x7fffu + ((v.u >> 16) & 1u);
  return (u16)(r >> 16);
}
static __device__ __forceinline__ float bf2f(u16 b) {
  union { unsigned u; float f; } v; v.u = ((unsigned)b) << 16;
  return v.f;
}
static __device__ __forceinline__ unsigned fmax_key(float f) {
  union { float f; unsigned u; } v; v.f = f;
  return (v.u & 0x80000000u) ? ~v.u : (v.u | 0x80000000u);
}
static __device__ __forceinline__ float fmax_unkey(unsigned k) {
  union { unsigned u; float f; } v;
  v.u = (k & 0x80000000u) ? (k ^ 0x80000000u) : ~k;
  return v.f;
}
static __device__ __forceinline__ f4v mfma16(s8v a, s8v b, f4v c) {
  return __builtin_amdgcn_mfma_f32_16x16x32_bf16(a, b, c, 0, 0, 0);
}
// Barrier draining LDS ops only (register-destined global loads stay in flight).
static __device__ __forceinline__ void bar_lds() {
  asm volatile("s_waitcnt lgkmcnt(0)" ::: "memory");
  __builtin_amdgcn_s_barrier();
}
// 8x f32 -> 8x bf16 (RNE) via v_cvt_pk_bf16_f32 (no builtin on gfx950).
static __device__ __forceinline__ s8v pack8(f4v a, f4v b) {
  union { s8v v; unsigned u[4]; } r;
  asm("v_cvt_pk_bf16_f32 %0, %1, %2" : "=v"(r.u[0]) : "v"(a[0]), "v"(a[1]));
  asm("v_cvt_pk_bf16_f32 %0, %1, %2" : "=v"(r.u[1]) : "v"(a[2]), "v"(a[3]));
  asm("v_cvt_pk_bf16_f32 %0, %1, %2" : "=v"(r.u[2]) : "v"(b[0]), "v"(b[1]));
  asm("v_cvt_pk_bf16_f32 %0, %1, %2" : "=v"(r.u[3]) : "v"(b[2]), "v"(b[3]));
  return r.v;
}
// XOR-swizzled element offset in a [R][ldc] bf16 tile (16B-chunk ^ row&7).
static __device__ __forceinline__ int sw(int row, int col, int ldc) {
  int c3 = col >> 3;
  c3 = (c3 & ~7) | ((c3 ^ row) & 7);
  return row * ldc + (c3 << 3) + (col & 7);
}

// ---------------------------------------------------------------------------
// One-shot weight conversion: [Wq|Wk|Wv|W0] f32 -> bf16, proj*dn -> bf16.
__global__ __launch_bounds__(256) void convw_k(
    const float* __restrict__ Wq, const float* __restrict__ Wk,
    const float* __restrict__ Wv, const float* __restrict__ W0,
    const float* __restrict__ proj, u16* __restrict__ out) {
  const int i = blockIdx.x * 256 + threadIdx.x;  // 8-elem group, 132096 total
  const float* s;
  float scale = 1.f;
  if (i < 131072) {
    const int zz = i >> 15;
    s = (zz == 0 ? Wq : zz == 1 ? Wk : zz == 2 ? Wv : W0) + (size_t)(i & 32767) * 8;
  } else {
    s = proj + (size_t)(i - 131072) * 8;
    scale = DN_;
  }
  f4v a = *(const f4v*)s, b = *(const f4v*)(s + 4);
#pragma unroll
  for (int j = 0; j < 4; j++) { a[j] *= scale; b[j] *= scale; }
  *(s8v*)(out + (size_t)i * 8) = pack8(a, b);
}

// ---------------------------------------------------------------------------
// Fused q/k/v projection: z = blockIdx.z. z=0 -> q_b, z=1 -> k_b,
// z=2 -> transposed store directly into vT.
// A: [16384,512] f32, W: bf16. 128x128 tile, BK=64, 4 waves 2x2, grid (128,4,3).
// Double-buffered LDS: 1 barrier per K-tile.
__global__ __launch_bounds__(256) void gemm3_k(
    const float* __restrict__ Aq, const float* __restrict__ Ak, const float* __restrict__ Av,
    const u16* __restrict__ Wb,
    const float* __restrict__ bq, const float* __restrict__ bk, const float* __restrict__ bv,
    u16* __restrict__ Cq, u16* __restrict__ Ck, u16* __restrict__ vT) {
  const int z = blockIdx.z;
  const float* Ap = (z == 0) ? Aq : (z == 1) ? Ak : Av;
  const u16* Bm = Wb + (size_t)z * 262144;
  const float* bias = (z == 0) ? bq : (z == 1) ? bk : bv;

  __shared__ u16 LB[4][8192];   // {Al0,Bl0,Al1,Bl1}; z=2 reuses first 32KB
  const int tid = threadIdx.x;
  const int r0 = blockIdx.x * 128, c0 = blockIdx.y * 128;
  const int lane = tid & 63, w = tid >> 6;
  const int l15 = lane & 15, l4 = lane >> 4;
  const int wr = (w >> 1) * 64, wc = (w & 1) * 64;
  const f4v z4 = {0.f, 0.f, 0.f, 0.f};
  f4v acc[4][4];
#pragma unroll
  for (int m = 0; m < 4; m++)
#pragma unroll
    for (int n = 0; n < 4; n++) acc[m][n] = z4;

  f4v pa0_0, pa0_1, pa1_0, pa1_1, pa2_0, pa2_1, pa3_0, pa3_1;
  s8v pb0, pb1, pb2, pb3;

#define LOADT(kt)                                                             \
  {                                                                           \
    const int u0 = tid, u1 = tid + 256, u2 = tid + 512, u3 = tid + 768;       \
    const float* s0 = Ap + (size_t)(r0 + (u0 >> 3)) * 512 + (kt) + ((u0 & 7) << 3); \
    const float* s1 = Ap + (size_t)(r0 + (u1 >> 3)) * 512 + (kt) + ((u1 & 7) << 3); \
    const float* s2 = Ap + (size_t)(r0 + (u2 >> 3)) * 512 + (kt) + ((u2 & 7) << 3); \
    const float* s3 = Ap + (size_t)(r0 + (u3 >> 3)) * 512 + (kt) + ((u3 & 7) << 3); \
    pa0_0 = *(const f4v*)s0; pa0_1 = *(const f4v*)(s0 + 4);                   \
    pa1_0 = *(const f4v*)s1; pa1_1 = *(const f4v*)(s1 + 4);                   \
    pa2_0 = *(const f4v*)s2; pa2_1 = *(const f4v*)(s2 + 4);                   \
    pa3_0 = *(const f4v*)s3; pa3_1 = *(const f4v*)(s3 + 4);                   \
    pb0 = *(const s8v*)(Bm + (size_t)(c0 + (u0 >> 3)) * 512 + (kt) + ((u0 & 7) << 3)); \
    pb1 = *(const s8v*)(Bm + (size_t)(c0 + (u1 >> 3)) * 512 + (kt) + ((u1 & 7) << 3)); \
    pb2 = *(const s8v*)(Bm + (size_t)(c0 + (u2 >> 3)) * 512 + (kt) + ((u2 & 7) << 3)); \
    pb3 = *(const s8v*)(Bm + (size_t)(c0 + (u3 >> 3)) * 512 + (kt) + ((u3 & 7) << 3)); \
  }
#define WRITET(Ad, Bd)                                                        \
  {                                                                           \
    const int u0 = tid, u1 = tid + 256, u2 = tid + 512, u3 = tid + 768;       \
    const int d0 = sw(u0 >> 3, (u0 & 7) << 3, 64);                            \
    const int d1 = sw(u1 >> 3, (u1 & 7) << 3, 64);                            \
    const int d2 = sw(u2 >> 3, (u2 & 7) << 3, 64);                            \
    const int d3 = sw(u3 >> 3, (u3 & 7) << 3, 64);                            \
    *(s8v*)&(Ad)[d0] = pack8(pa0_0, pa0_1); *(s8v*)&(Bd)[d0] = pb0;           \
    *(s8v*)&(Ad)[d1] = pack8(pa1_0, pa1_1); *(s8v*)&(Bd)[d1] = pb1;           \
    *(s8v*)&(Ad)[d2] = pack8(pa2_0, pa2_1); *(s8v*)&(Bd)[d2] = pb2;           \
    *(s8v*)&(Ad)[d3] = pack8(pa3_0, pa3_1); *(s8v*)&(Bd)[d3] = pb3;           \
  }

  LOADT(0);
  WRITET(LB[0], LB[1]);
  bar_lds();

#pragma unroll
  for (int t = 0; t < 8; t++) {
    u16* const Ac = LB[(t & 1) * 2];
    u16* const Bc = LB[(t & 1) * 2 + 1];
    u16* const An = LB[((t + 1) & 1) * 2];
    u16* const Bn = LB[((t + 1) & 1) * 2 + 1];
    if (t < 7) LOADT((t + 1) * 64);   // issue loads early (regs)
#pragma unroll
    for (int ks = 0; ks < 2; ks++) {
      s8v af[4], bf[4];
#pragma unroll
      for (int m = 0; m < 4; m++)
        af[m] = *(const s8v*)&Ac[sw(wr + m * 16 + l15, ks * 32 + l4 * 8, 64)];
#pragma unroll
      for (int n = 0; n < 4; n++)
        bf[n] = *(const s8v*)&Bc[sw(wc + n * 16 + l15, ks * 32 + l4 * 8, 64)];
#pragma unroll
      for (int m = 0; m < 4; m++)
#pragma unroll
        for (int n = 0; n < 4; n++) acc[m][n] = mfma16(af[m], bf[n], acc[m][n]);
    }
    if (t < 7) WRITET(An, Bn);        // write late, into the other buffer
    bar_lds();                        // single barrier per K-tile
  }
#undef LOADT
#undef WRITET

  if (z == 2) {
    // scatter biased bf16 tile into LB as [channel][l-chunk-swizzled]
    u16* const T = &LB[0][0];  // 16384 u16 (LB[0]+LB[1] contiguous)
#pragma unroll
    for (int n = 0; n < 4; n++) {
      const int cc = wc + n * 16 + l15;
      const float bv_ = bias[c0 + cc];
#pragma unroll
      for (int m = 0; m < 4; m++)
#pragma unroll
        for (int r = 0; r < 4; r++) {
          const int ll = wr + m * 16 + l4 * 4 + r;
          const int ch = ll >> 3;
          const int chs = (ch & 8) | ((ch ^ cc) & 7);
          T[cc * 128 + chs * 8 + (ll & 7)] = f2bf(acc[m][n][r] + bv_);
        }
    }
    __syncthreads();
    const int b = r0 >> 12, l0 = r0 & 4095;
    for (int u = tid; u < 2048; u += 256) {
      const int cc = u >> 4, ch = u & 15;
      const int chs = (ch & 8) | ((ch ^ cc) & 7);
      const s8v o = *(const s8v*)&T[cc * 128 + chs * 8];
      *(s8v*)(vT + ((size_t)(b * 512 + c0 + cc)) * 4096 + l0 + ch * 8) = o;
    }
    return;
  }
  u16* const Cp = (z == 0) ? Cq : Ck;
#pragma unroll
  for (int n = 0; n < 4; n++) {
    const int col = c0 + wc + n * 16 + l15;
    const float bv_ = bias[col];
#pragma unroll
    for (int m = 0; m < 4; m++)
#pragma unroll
      for (int r = 0; r < 4; r++) {
        const int row = r0 + wr + m * 16 + l4 * 4 + r;
        Cp[(size_t)row * 512 + col] = f2bf(acc[m][n][r] + bv_);
      }
  }
}

// ---------------------------------------------------------------------------
// Final GEMM: C = A @ W0^T + b0. A bf16, W0b bf16, C f32. 128x128 tile,
// grid (128,4). Double-buffered LDS: 1 barrier per K-tile.
__global__ __launch_bounds__(256) void gemm_bt(const u16* __restrict__ Ap,
                                               const u16* __restrict__ Bm,
                                               const float* __restrict__ bias,
                                               float* __restrict__ Cp) {
  __shared__ u16 LB[4][8192];   // {Al0,Bl0,Al1,Bl1}
  const int tid = threadIdx.x;
  const int r0 = blockIdx.x * 128, c0 = blockIdx.y * 128;
  const int lane = tid & 63, w = tid >> 6;
  const int l15 = lane & 15, l4 = lane >> 4;
  const int wr = (w >> 1) * 64, wc = (w & 1) * 64;
  const f4v z = {0.f, 0.f, 0.f, 0.f};
  f4v acc[4][4];
#pragma unroll
  for (int m = 0; m < 4; m++)
#pragma unroll
    for (int n = 0; n < 4; n++) acc[m][n] = z;

  s8v qa0, qa1, qa2, qa3, qb0, qb1, qb2, qb3;
#define LOADT(kt)                                                             \
  {                                                                           \
    const int u0 = tid, u1 = tid + 256, u2 = tid + 512, u3 = tid + 768;       \
    qa0 = *(const s8v*)(Ap + (size_t)(r0 + (u0 >> 3)) * 512 + (kt) + ((u0 & 7) << 3)); \
    qa1 = *(const s8v*)(Ap + (size_t)(r0 + (u1 >> 3)) * 512 + (kt) + ((u1 & 7) << 3)); \
    qa2 = *(const s8v*)(Ap + (size_t)(r0 + (u2 >> 3)) * 512 + (kt) + ((u2 & 7) << 3)); \
    qa3 = *(const s8v*)(Ap + (size_t)(r0 + (u3 >> 3)) * 512 + (kt) + ((u3 & 7) << 3)); \
    qb0 = *(const s8v*)(Bm + (size_t)(c0 + (u0 >> 3)) * 512 + (kt) + ((u0 & 7) << 3)); \
    qb1 = *(const s8v*)(Bm + (size_t)(c0 + (u1 >> 3)) * 512 + (kt) + ((u1 & 7) << 3)); \
    qb2 = *(const s8v*)(Bm + (size_t)(c0 + (u2 >> 3)) * 512 + (kt) + ((u2 & 7) << 3)); \
    qb3 = *(const s8v*)(Bm + (size_t)(c0 + (u3 >> 3)) * 512 + (kt) + ((u3 & 7) << 3)); \
  }
#define WRITET(Ad, Bd)                                                        \
  {                                                                           \
    const int u0 = tid, u1 = tid + 256, u2 = tid + 512, u3 = tid + 768;       \
    const int d0 = sw(u0 >> 3, (u0 & 7) << 3, 64);                            \
    const int d1 = sw(u1 >> 3, (u1 & 7) << 3, 64);                            \
    const int d2 = sw(u2 >> 3, (u2 & 7) << 3, 64);                            \
    const int d3 = sw(u3 >> 3, (u3 & 7) << 3, 64);                            \
    *(s8v*)&(Ad)[d0] = qa0; *(s8v*)&(Bd)[d0] = qb0;                           \
    *(s8v*)&(Ad)[d1] = qa1; *(s8v*)&(Bd)[d1] = qb1;                           \
    *(s8v*)&(Ad)[d2] = qa2; *(s8v*)&(Bd)[d2] = qb2;                           \
    *(s8v*)&(Ad)[d3] = qa3; *(s8v*)&(Bd)[d3] = qb3;                           \
  }

  LOADT(0);
  WRITET(LB[0], LB[1]);
  bar_lds();

#pragma unroll
  for (int t = 0; t < 8; t++) {
    u16* const Ac = LB[(t & 1) * 2];
    u16* const Bc = LB[(t & 1) * 2 + 1];
    u16* const An = LB[((t + 1) & 1) * 2];
    u16* const Bn = LB[((t + 1) & 1) * 2 + 1];
    if (t < 7) LOADT((t + 1) * 64);
#pragma unroll
    for (int ks = 0; ks < 2; ks++) {
      s8v af[4], bf[4];
#pragma unroll
      for (int m = 0; m < 4; m++)
        af[m] = *(const s8v*)&Ac[sw(wr + m * 16 + l15, ks * 32 + l4 * 8, 64)];
#pragma unroll
      for (int n = 0; n < 4; n++)
        bf[n] = *(const s8v*)&Bc[sw(wc + n * 16 + l15, ks * 32 + l4 * 8, 64)];
#pragma unroll
      for (int m = 0; m < 4; m++)
#pragma unroll
        for (int n = 0; n < 4; n++) acc[m][n] = mfma16(af[m], bf[n], acc[m][n]);
    }
    if (t < 7) WRITET(An, Bn);
    bar_lds();
  }
#undef LOADT
#undef WRITET

#pragma unroll
  for (int n = 0; n < 4; n++) {
    const int col = c0 + wc + n * 16 + l15;
    const float bv = bias[col];
#pragma unroll
    for (int m = 0; m < 4; m++)
#pragma unroll
      for (int r = 0; r < 4; r++) {
        const int row = r0 + wr + m * 16 + l4 * 4 + r;
        Cp[(size_t)row * 512 + col] = acc[m][n][r] + bv;
      }
  }
}

// ---------------------------------------------------------------------------
// Merged feature-map pass: blocks 0..1023 = query (MODE0 -> qp),
// blocks 1024..2047 = key pass1 (MODE1 -> global per-(b,h) max atomics).
__global__ __launch_bounds__(256) void feat01_k(const u16* __restrict__ q_b,
                                                const u16* __restrict__ k_b,
                                                const u16* __restrict__ pDN,
                                                u16* __restrict__ qp,
                                                unsigned* __restrict__ slots) {
  __shared__ u16 Xl[128 * 64];
  __shared__ u16 Pl[128 * 64];
  __shared__ float diag_l[128];
  __shared__ unsigned hmax8[8];
  const int mode = blockIdx.x >> 10;
  const int r0 = (blockIdx.x & 1023) * 128;
  const u16* X = mode ? k_b : q_b;
  const int tid = threadIdx.x;
  if (mode && tid < 8) hmax8[tid] = 0u;
  for (int u = tid; u < 1024; u += 256) {
    const int row = u >> 3, c8 = (u & 7) << 3;
    *(s8v*)&Xl[sw(row, c8, 64)] = *(const s8v*)(X + (size_t)r0 * 64 + u * 8);
    *(s8v*)&Pl[sw(row, c8, 64)] = *(const s8v*)(pDN + u * 8);
  }
  __syncthreads();
  if (!mode && tid < 128) {
    float s = 0.f;
#pragma unroll
    for (int c = 0; c < 8; c++) {
      s8v v = *(const s8v*)&Xl[sw(tid, c * 8, 64)];
#pragma unroll
      for (int jj = 0; jj < 8; jj++) { float x = bf2f((u16)v[jj]); s += x * x; }
    }
    diag_l[tid] = 0.0625f * s;  // 0.5*dn^2
  }
  __syncthreads();
  const int lane = tid & 63, w = tid >> 6, l15 = lane & 15, l4 = lane >> 4;
  const f4v z = {0.f, 0.f, 0.f, 0.f};
  f4v acc[2][8];
#pragma unroll
  for (int m = 0; m < 2; m++)
#pragma unroll
    for (int n = 0; n < 8; n++) acc[m][n] = z;
#pragma unroll
  for (int ks = 0; ks < 2; ks++) {
    s8v af[2];
#pragma unroll
    for (int m = 0; m < 2; m++)
      af[m] = *(const s8v*)&Xl[sw(w * 32 + m * 16 + l15, ks * 32 + l4 * 8, 64)];
#pragma unroll
    for (int n = 0; n < 8; n++) {
      const s8v bf = *(const s8v*)&Pl[sw(n * 16 + l15, ks * 32 + l4 * 8, 64)];
#pragma unroll
      for (int m = 0; m < 2; m++) acc[m][n] = mfma16(af[m], bf, acc[m][n]);
    }
  }
#pragma unroll
  for (int m = 0; m < 2; m++)
#pragma unroll
    for (int r = 0; r < 4; r++) {
      const int rowl = w * 32 + m * 16 + l4 * 4 + r;
      const int R = r0 + rowl;
      float mx = acc[m][0][r];
#pragma unroll
      for (int n = 1; n < 8; n++) mx = fmaxf(mx, acc[m][n][r]);
      mx = fmaxf(mx, __shfl_xor(mx, 1, 64));
      mx = fmaxf(mx, __shfl_xor(mx, 2, 64));
      mx = fmaxf(mx, __shfl_xor(mx, 4, 64));
      mx = fmaxf(mx, __shfl_xor(mx, 8, 64));
      if (mode) {
        if (l15 == 0) atomicMax(&hmax8[(l4 * 4 + r) & 7], fmax_key(mx));
      } else {
        const float sub = diag_l[rowl] + mx;
        const size_t ob = (size_t)R * 128 + l15;
#pragma unroll
        for (int n = 0; n < 8; n++)
          qp[ob + n * 16] = f2bf(RATIO_ * (expf(acc[m][n][r] - sub) + EPS_));
      }
    }
  if (mode) {
    __syncthreads();
    if (tid < 8) atomicMax(&slots[((r0 >> 15) << 3) | tid], hmax8[tid]);
  }
}

// ---------------------------------------------------------------------------
// Fused key pass 2 + scan1. One (bh, chunk) per block over 128 l-rows:
// recompute dash, exp with global max -> write kp; build kp^T tile in LDS (S);
// then ST[d][m] = sum_l v[l,d]*kp[l,m] via MFMA from S + Vl, plus colsum.
__global__ __launch_bounds__(256) void featsc_k(const u16* __restrict__ k_b,
                                                const u16* __restrict__ pDN,
                                                const u16* __restrict__ vT,
                                                const unsigned* __restrict__ slots,
                                                u16* __restrict__ kp,
                                                u16* __restrict__ st,
                                                float* __restrict__ colsum) {
  __shared__ u16 S[16384];   // Xl=[0:8192), Pl=[8192:16384); then kp^T tile [m][l]
  __shared__ u16 Vl[8192];   // vT tile [d=64][l=128] sw-layout
  __shared__ float diag_l[128];
  u16* const Xl = S;
  u16* const Pl = S + 8192;
  const int c = blockIdx.x, bh = blockIdx.y;
  const int b = bh >> 3, h = bh & 7;
  const int l0 = c * 128;
  const int tid = threadIdx.x;
  for (int u = tid; u < 1024; u += 256) {
    const int row = u >> 3, c8 = (u & 7) << 3;
    *(s8v*)&Xl[sw(row, c8, 64)] =
        *(const s8v*)(k_b + ((size_t)(b * 4096 + l0 + row)) * 512 + h * 64 + c8);
    *(s8v*)&Pl[sw(row, c8, 64)] = *(const s8v*)(pDN + u * 8);
  }
  for (int u = tid; u < 1024; u += 256) {
    const int row = u >> 4, c8 = (u & 15) * 8;
    *(s8v*)&Vl[sw(row, c8, 128)] =
        *(const s8v*)(vT + ((size_t)(bh * 64 + row)) * 4096 + c * 128 + c8);
  }
  __syncthreads();
  if (tid < 128) {
    float s = 0.f;
#pragma unroll
    for (int cc = 0; cc < 8; cc++) {
      s8v v = *(const s8v*)&Xl[sw(tid, cc * 8, 64)];
#pragma unroll
      for (int jj = 0; jj < 8; jj++) { float x = bf2f((u16)v[jj]); s += x * x; }
    }
    diag_l[tid] = 0.0625f * s;
  }
  __syncthreads();
  const int lane = tid & 63, w = tid >> 6, l15 = lane & 15, l4 = lane >> 4;
  const f4v z = {0.f, 0.f, 0.f, 0.f};
  f4v acc[2][8];
#pragma unroll
  for (int m = 0; m < 2; m++)
#pragma unroll
    for (int n = 0; n < 8; n++) acc[m][n] = z;
#pragma unroll
  for (int ks = 0; ks < 2; ks++) {
    s8v af[2];
#pragma unroll
    for (int m = 0; m < 2; m++)
      af[m] = *(const s8v*)&Xl[sw(w * 32 + m * 16 + l15, ks * 32 + l4 * 8, 64)];
#pragma unroll
    for (int n = 0; n < 8; n++) {
      const s8v bf = *(const s8v*)&Pl[sw(n * 16 + l15, ks * 32 + l4 * 8, 64)];
#pragma unroll
      for (int m = 0; m < 2; m++) acc[m][n] = mfma16(af[m], bf, acc[m][n]);
    }
  }
  const float gmax = fmax_unkey(slots[bh]);
  __syncthreads();   // all Xl/Pl reads done; S becomes the kp^T tile
#pragma unroll
  for (int mm = 0; mm < 2; mm++)
#pragma unroll
    for (int r = 0; r < 4; r++) {
      const int ll = w * 32 + mm * 16 + l4 * 4 + r;
      const float sub = diag_l[ll] + gmax;
      const size_t ob = ((size_t)(b * 4096 + l0 + ll) * 8 + h) * 128 + l15;
#pragma unroll
      for (int n = 0; n < 8; n++) {
        const u16 val = f2bf(RATIO_ * (expf(acc[mm][n][r] - sub) + EPS_));
        kp[ob + n * 16] = val;
        const int m = n * 16 + l15;
        S[sw(m, ll, 128)] = val;
      }
    }
  __syncthreads();

  // scan1 part: ST[d=64][m=128] = sum_l Vl[d][l] * S[m][l]; colsum[m] = sum_l S[m][l]
  f4v acc1[8];
#pragma unroll
  for (int n = 0; n < 8; n++) acc1[n] = z;
#pragma unroll
  for (int ks = 0; ks < 4; ks++) {
    const s8v af = *(const s8v*)&Vl[sw(w * 16 + l15, ks * 32 + l4 * 8, 128)];
#pragma unroll
    for (int n = 0; n < 8; n++) {
      const s8v bf = *(const s8v*)&S[sw(n * 16 + l15, ks * 32 + l4 * 8, 128)];
      acc1[n] = mfma16(af, bf, acc1[n]);
    }
  }
  if (tid < 128) {
    float s = 0.f;
#pragma unroll
    for (int j8 = 0; j8 < 16; j8++) {
      s8v v = *(const s8v*)&S[sw(tid, j8 * 8, 128)];
#pragma unroll
      for (int jj = 0; jj < 8; jj++) s += bf2f((u16)v[jj]);
    }
    colsum[((size_t)(bh * 32 + c)) * 128 + tid] = s;
  }
  const size_t base = ((size_t)(bh * 32 + c)) * 8192;
#pragma unroll
  for (int n = 0; n < 8; n++)
#pragma unroll
    for (int r = 0; r < 4; r++)
      st[base + (w * 16 + l4 * 4 + r) * 128 + n * 16 + l15] = f2bf(acc1[n][r]);
}

// merged scan phase 2 + kpref: grid (9, 32). seg<8: in-place exclusive prefix
// of st; seg==8: exclusive prefix of colsum -> kpref (threads 0..127).
__global__ __launch_bounds__(256) void scan2p_k(u16* __restrict__ st,
                                                const float* __restrict__ colsum,
                                                float* __restrict__ kpref) {
  const int seg = blockIdx.x, bh = blockIdx.y, tid = threadIdx.x;
  if (seg < 8) {
    const int e0 = seg * 1024 + tid * 4;
    float acc[4] = {0.f, 0.f, 0.f, 0.f};
    for (int c = 0; c < 32; c++) {
      u16* p = st + ((size_t)(bh * 32 + c)) * 8192 + e0;
      u4v v = *(u4v*)p, o;
#pragma unroll
      for (int j = 0; j < 4; j++) {
        const float x = bf2f(v[j]);
        o[j] = f2bf(acc[j]);
        acc[j] += x;
      }
      *(u4v*)p = o;
    }
  } else if (tid < 128) {
    float ka = 0.f;
    for (int c = 0; c < 32; c++) {
      kpref[(bh * 32 + c) * 128 + tid] = ka;
      ka += colsum[(bh * 32 + c) * 128 + tid];
    }
  }
}

// scan phase 3 (merged halves): one 512-thread block per (chunk, bh).
__global__ __launch_bounds__(512) void scan3_k(const u16* __restrict__ qp,
                                               const u16* __restrict__ kp,
                                               const u16* __restrict__ vT,
                                               const u16* __restrict__ st,
                                               const float* __restrict__ kpref,
                                               u16* __restrict__ attn) {
  __shared__ u16 Ql[128 * 128];  // 32KB; front 16KB reused as Vl in AV phase
  __shared__ u16 Kr[128 * 128];  // 32KB; reused as Al(128x128) in AV phase
  const int c = blockIdx.x, bh = blockIdx.y;
  const int b = bh >> 3, h = bh & 7;
  const int tid = threadIdx.x, lane = tid & 63, w = tid >> 6;
  const int l15 = lane & 15, l4 = lane >> 4;
  const size_t Rbase = ((size_t)(b * 4096 + c * 128)) * 8 + h;

  for (int u = tid; u < 2048; u += 512) {
    const int row = u >> 4, c8 = (u & 15) * 8;
    *(s8v*)&Ql[sw(row, c8, 128)] =
        *(const s8v*)(qp + (Rbase + (size_t)row * 8) * 128 + c8);
    *(s8v*)&Kr[sw(row, c8, 128)] =
        *(const s8v*)(kp + (Rbase + (size_t)row * 8) * 128 + c8);
  }
  __syncthreads();

  const f4v z = {0.f, 0.f, 0.f, 0.f};
  f4v sc[8];
#pragma unroll
  for (int n = 0; n < 8; n++) sc[n] = z;
#pragma unroll
  for (int ks = 0; ks < 4; ks++) {
    const s8v af = *(const s8v*)&Ql[sw(w * 16 + l15, ks * 32 + l4 * 8, 128)];
#pragma unroll
    for (int n = 0; n < 8; n++) {
      const s8v bf = *(const s8v*)&Kr[sw(n * 16 + l15, ks * 32 + l4 * 8, 128)];
      sc[n] = mfma16(af, bf, sc[n]);
    }
  }
  const int lb = w * 16 + l4 * 4;
  float rs[4];
#pragma unroll
  for (int r = 0; r < 4; r++) {
    float s = 0.f;
#pragma unroll
    for (int n = 0; n < 8; n++) {
      const int col = n * 16 + l15;
      const float v = (col <= lb + r) ? sc[n][r] : 0.f;
      sc[n][r] = v;
      s += v;
    }
    s += __shfl_xor(s, 1, 64);
    s += __shfl_xor(s, 2, 64);
    s += __shfl_xor(s, 4, 64);
    s += __shfl_xor(s, 8, 64);
    rs[r] = s;
  }
  __syncthreads();

  {
    const u16* pref = st + ((size_t)(bh * 32 + c)) * 8192;
    for (int u = tid; u < 1024; u += 512) {
      const int row = u >> 4, c8 = (u & 15) * 8;
      *(s8v*)&Kr[sw(row, c8, 128)] = *(const s8v*)(pref + u * 8);
    }
    if (tid < 128) Kr[sw(64, tid, 128)] = f2bf(kpref[(bh * 32 + c) * 128 + tid]);
    for (int i = tid; i < 15 * 128; i += 512) Kr[65 * 128 + i] = 0;
  }
  __syncthreads();

  f4v acc2[5];
#pragma unroll
  for (int n = 0; n < 5; n++) acc2[n] = z;
#pragma unroll
  for (int ks = 0; ks < 4; ks++) {
    const s8v af = *(const s8v*)&Ql[sw(w * 16 + l15, ks * 32 + l4 * 8, 128)];
#pragma unroll
    for (int n = 0; n < 5; n++) {
      const s8v bf = *(const s8v*)&Kr[sw(n * 16 + l15, ks * 32 + l4 * 8, 128)];
      acc2[n] = mfma16(af, bf, acc2[n]);
    }
  }
  float din[4];
#pragma unroll
  for (int r = 0; r < 4; r++) {
    float s = acc2[4][r];
    s += __shfl_xor(s, 1, 64);
    s += __shfl_xor(s, 2, 64);
    s += __shfl_xor(s, 4, 64);
    s += __shfl_xor(s, 8, 64);
    din[r] = s;
  }
  __syncthreads();

#pragma unroll
  for (int n = 0; n < 8; n++)
#pragma unroll
    for (int r = 0; r < 4; r++)
      Kr[sw(w * 16 + l4 * 4 + r, n * 16 + l15, 128)] = f2bf(sc[n][r]);
  for (int u = tid; u < 1024; u += 512) {
    const int row = u >> 4, c8 = (u & 15) * 8;
    *(s8v*)&Ql[sw(row, c8, 128)] =
        *(const s8v*)(vT + ((size_t)(bh * 64 + row)) * 4096 + c * 128 + c8);
  }
  __syncthreads();

#pragma unroll
  for (int ks = 0; ks < 4; ks++) {
    const s8v af = *(const s8v*)&Kr[sw(w * 16 + l15, ks * 32 + l4 * 8, 128)];
#pragma unroll
    for (int n = 0; n < 4; n++) {
      const s8v bf = *(const s8v*)&Ql[sw(n * 16 + l15, ks * 32 + l4 * 8, 128)];
      acc2[n] = mfma16(af, bf, acc2[n]);
    }
  }
#pragma unroll
  for (int r = 0; r < 4; r++) {
    const float den = rs[r] + din[r];
    const int lrow = w * 16 + l4 * 4 + r;
    const size_t ob = ((size_t)(b * 4096 + c * 128 + lrow)) * 512 + h * 64;
#pragma unroll
    for (int n = 0; n < 4; n++)
      attn[ob + n * 16 + l15] = f2bf(acc2[n][r] / den);
  }
}

// ---------------------------------------------------------------------------
extern "C" void kernel_launch(void* const* d_in, const int* in_sizes, int n_in,
                              void* d_out, int out_size, void* d_ws, size_t ws_size,
                              hipStream_t stream) {
  const float* query = (const float*)d_in[0];
  const float* key   = (const float*)d_in[1];
  const float* value = (const float*)d_in[2];
  const float* Wq = (const float*)d_in[3];
  const float* Wk = (const float*)d_in[4];
  const float* Wv = (const float*)d_in[5];
  const float* W0 = (const float*)d_in[6];
  const float* bq = (const float*)d_in[7];
  const float* bk = (const float*)d_in[8];
  const float* bv = (const float*)d_in[9];
  const float* b0 = (const float*)d_in[10];
  const float* proj = (const float*)d_in[11];

  char* ws = (char*)d_ws;
  const size_t MB = 1u << 20;
  u16* kp   = (u16*)(ws + 0);            // 32MB
  u16* k_b  = (u16*)(ws + 32 * MB);      // 16MB
  u16* attn = (u16*)(ws + 32 * MB);      // alias k_b (dead after featsc)
  float* colsum = (float*)(ws + 32 * MB);// 512KB alias (dead before attn write)
  u16* qp   = (u16*)(ws + 48 * MB);      // 32MB
  u16* q_b  = (u16*)(ws + 80 * MB);      // 16MB
  u16* st   = (u16*)(ws + 112 * MB);     // 16MB
  u16* vT   = (u16*)(ws + 128 * MB);     // 16MB
  float* kpref    = (float*)(ws + 144 * MB);             // 512KB
  unsigned* slots = (unsigned*)(ws + 144 * MB + 524288); // 128B
  u16* Wb   = (u16*)(ws + 145 * MB);     // [Wq|Wk|Wv|W0] bf16 + dn*proj bf16
  u16* pDN  = Wb + 4 * 262144;

  (void)hipMemsetAsync(slots, 0, 32 * sizeof(unsigned), stream);

  dim3 blk(256);
  convw_k<<<dim3(516), blk, 0, stream>>>(Wq, Wk, Wv, W0, proj, Wb);
  gemm3_k<<<dim3(128, 4, 3), blk, 0, stream>>>(query, key, value, Wb,
                                               bq, bk, bv, q_b, k_b, vT);
  feat01_k<<<dim3(2048), blk, 0, stream>>>(q_b, k_b, pDN, qp, slots);
  featsc_k<<<dim3(32, 32), blk, 0, stream>>>(k_b, pDN, vT, slots, kp, st, colsum);
  scan2p_k<<<dim3(9, 32), blk, 0, stream>>>(st, colsum, kpref);
  scan3_k<<<dim3(32, 32), dim3(512), 0, stream>>>(qp, kp, vT, st, kpref, attn);
  gemm_bt<<<dim3(128, 4), blk, 0, stream>>>(attn, Wb + 3 * 262144, b0, (float*)d_out);
}